// Round 14
// baseline (8199.136 us; speedup 1.0000x reference)
//
#include <hip/hip_runtime.h>
#include <hip/hip_bf16.h>
#include <math.h>

using bf16 = __hip_bfloat16;

#define BB   4
#define TT   2048
#define DD   1024
#define HH   16
#define HD_  64
#define LAT_ 128
#define RP   32
#define EPS_ 1e-6f

// ---------------------------------------------------------------------------
// R14 KEY FIX: d_out is an FP32 buffer (reference returns float32; harness
// truncates each fp32 to bf16 for comparison). R2-R13 wrote bf16 into it,
// so the harness compared ref[k] vs out[2k+1] — decorrelated forever.
// Pipeline below = R4's triple-verified naive semantics, fp32 output.
// ---------------------------------------------------------------------------

__global__ __launch_bounds__(256)
void sentinel_kernel(float* __restrict__ out, float val, long long n)
{
    long long i = (long long)blockIdx.x * 256 + threadIdx.x;
    if (i < n) out[i] = val;
}

// ---------------------------------------------------------------------------
// Naive GEMM, one thread per output: C[M,N] = A[M,K] @ B[K,N], row-major,
// fp32 in / fp32 out.
// ---------------------------------------------------------------------------
__global__ __launch_bounds__(256)
void naive_gemm(const float* __restrict__ A, const float* __restrict__ B,
                float* __restrict__ C, int M, int N, int K)
{
    const long long idx = (long long)blockIdx.x * 256 + threadIdx.x;
    if (idx >= (long long)M * N) return;
    const int row = (int)(idx / N);
    const int col = (int)(idx % N);
    float acc = 0.f;
    const float* a = A + (size_t)row * K;
    const float* b = B + col;
    for (int k = 0; k < K; ++k) acc = fmaf(a[k], b[(size_t)k * N], acc);
    C[(size_t)row * N + col] = acc;
}

// ---------------------------------------------------------------------------
// Q RMSNorm: one wave64 per (bt, h); rms over 64 head dims; write first 32
// normalized dims (only those feed scores) to qn bf16 (b,h,t,32).
// ---------------------------------------------------------------------------
__global__ __launch_bounds__(256)
void qrms_kernel(const float* __restrict__ qraw, const float* __restrict__ qg,
                 bf16* __restrict__ qn)
{
    const int gid  = blockIdx.x * 256 + threadIdx.x;
    const int lane = gid & 63;
    const int grp  = gid >> 6;       // (bt, h)
    const int bt   = grp >> 4;
    const int h    = grp & 15;
    float v = qraw[(size_t)bt * DD + h * HD_ + lane];
    float s = v * v;
    #pragma unroll
    for (int off = 32; off; off >>= 1) s += __shfl_xor(s, off, 64);
    const float inv = 1.0f / sqrtf(s * (1.0f / HD_) + EPS_);
    if (lane < RP) {
        const int b = bt >> 11, t = bt & 2047;   // T = 2048
        qn[(((size_t)(b * HH + h)) * TT + t) * RP + lane] =
            __float2bfloat16(qg[lane] * v * inv);
    }
}

// ---------------------------------------------------------------------------
// K RMSNorm over 32 rope dims (lanes 0..31) + V relayout (lanes 32..63).
// In: kpre/vraw fp32 (bt,512). Out: kn/vout bf16 (b,h,t,32).
// ---------------------------------------------------------------------------
__global__ __launch_bounds__(256)
void kv_split_kernel(const float* __restrict__ kpre, const float* __restrict__ vraw,
                     const float* __restrict__ kg,
                     bf16* __restrict__ kn, bf16* __restrict__ vout)
{
    const int gid  = blockIdx.x * 256 + threadIdx.x;
    const int lane = gid & 63;
    const int grp  = gid >> 6;
    const int bt   = grp >> 4;
    const int h    = grp & 15;
    const int b = bt >> 11, t = bt & 2047;
    const size_t dst = (((size_t)(b * HH + h)) * TT + t) * RP;
    if (lane < 32) {
        float v = kpre[(size_t)bt * 512 + h * 32 + lane];
        float s = v * v;
        #pragma unroll
        for (int off = 16; off; off >>= 1) s += __shfl_xor(s, off, 32);
        const float inv = 1.0f / sqrtf(s * (1.0f / RP) + EPS_);
        kn[dst + lane] = __float2bfloat16(kg[lane] * v * inv);
    } else {
        const int j = lane - 32;
        vout[dst + j] = __float2bfloat16(vraw[(size_t)bt * 512 + h * 32 + j]);
    }
}

// ---------------------------------------------------------------------------
// Two-pass causal attention: one wave64 per (b,h,t) query row; lane covers
// key positions s = lane, lane+64, ... <= t. fp32 accumulation.
// Writes att fp32 (b, t, h*64+c) with explicit zero pad of dims 32..63.
// ---------------------------------------------------------------------------
__global__ __launch_bounds__(64)
void attn_naive(const bf16* __restrict__ qn, const bf16* __restrict__ kn,
                const bf16* __restrict__ vv, float* __restrict__ att)
{
    const int t    = blockIdx.x;
    const int bh   = blockIdx.y;
    const int lane = threadIdx.x;

    const bf16* qp = qn + ((size_t)bh * TT + t) * RP;
    float q[RP];
    #pragma unroll
    for (int j = 0; j < RP; ++j) q[j] = __bfloat162float(qp[j]) * 0.125f; // 1/sqrt(64)

    float mloc = -1e30f;
    for (int s = lane; s <= t; s += 64) {
        const bf16* kp = kn + ((size_t)bh * TT + s) * RP;
        float d = 0.f;
        #pragma unroll
        for (int j = 0; j < RP; ++j) d = fmaf(q[j], __bfloat162float(kp[j]), d);
        mloc = fmaxf(mloc, d);
    }
    #pragma unroll
    for (int off = 32; off; off >>= 1) mloc = fmaxf(mloc, __shfl_xor(mloc, off, 64));

    float l = 0.f;
    float acc[RP];
    #pragma unroll
    for (int c = 0; c < RP; ++c) acc[c] = 0.f;
    for (int s = lane; s <= t; s += 64) {
        const bf16* kp = kn + ((size_t)bh * TT + s) * RP;
        float d = 0.f;
        #pragma unroll
        for (int j = 0; j < RP; ++j) d = fmaf(q[j], __bfloat162float(kp[j]), d);
        const float p = __expf(d - mloc);
        l += p;
        const bf16* vp = vv + ((size_t)bh * TT + s) * RP;
        #pragma unroll
        for (int c = 0; c < RP; ++c)
            acc[c] = fmaf(p, __bfloat162float(vp[c]), acc[c]);
    }
    #pragma unroll
    for (int off = 32; off; off >>= 1) l += __shfl_xor(l, off, 64);
    #pragma unroll
    for (int c = 0; c < RP; ++c) {
        float a = acc[c];
        #pragma unroll
        for (int off = 32; off; off >>= 1) a += __shfl_xor(a, off, 64);
        acc[c] = a;
    }

    if (lane == 0) {
        const int b = bh >> 4, h = bh & 15;
        const float inv = 1.0f / l;
        float* op = att + ((size_t)(b * TT + t)) * DD + h * HD_;
        #pragma unroll
        for (int c = 0; c < RP; ++c) op[c] = acc[c] * inv;
        #pragma unroll
        for (int c = RP; c < HD_; ++c) op[c] = 0.f;   // explicit zero pad
    }
}

// ---------------------------------------------------------------------------
// Workspace (BYTE offsets from base = d_ws + 64), ~60 MB, within verified ws:
//   [0, 33554432)  qraw fp32 (bt,1024); then kpre fp32 [0,16.7M),
//                  vraw fp32 [16.7M,33.5M); then att fp32 [0,33.5M)
//   [33554432, 41943040)  qn bf16 (b,h,t,32)
//   [41943040, 50331648)  kn bf16 (b,h,t,32)
//   [50331648, 58720256)  vb bf16 (b,h,t,32)
//   [58720256, 62914560)  kv fp32 (bt,128)
// ---------------------------------------------------------------------------
extern "C" void kernel_launch(void* const* d_in, const int* in_sizes, int n_in,
                              void* d_out, int out_size, void* d_ws, size_t ws_size,
                              hipStream_t stream)
{
    float* out = (float*)d_out;                     // FP32 output (the R14 fix)
    const long long NOUT = (long long)BB * TT * DD; // 8388608
    const int outgrid = (int)((NOUT + 255) / 256);

    // Environment tripwires (all validated silent R4-R13; fp32 sentinels now).
    static const long long expect[8] =
        {8388608, 1048576, 131072, 65536, 65536, 1048576, 64, 32};
    if (n_in != 8) {
        sentinel_kernel<<<outgrid, 256, 0, stream>>>(out, 20000.0f + 100.0f * n_in, NOUT);
        return;
    }
    for (int i = 0; i < 8; ++i) {
        if ((long long)in_sizes[i] != expect[i]) {
            sentinel_kernel<<<outgrid, 256, 0, stream>>>(out, 10000.0f + 1000.0f * i, NOUT);
            return;
        }
    }
    if (ws_size < 62914624ULL) {
        sentinel_kernel<<<outgrid, 256, 0, stream>>>(
            out, 30000.0f + (float)(ws_size >> 20), NOUT);
        return;
    }
    if (out_size != 8388608) {
        sentinel_kernel<<<outgrid, 256, 0, stream>>>(
            out, 512.0f * (1.0f + (float)(out_size >> 20)), NOUT);
        return;
    }

    const float* x   = (const float*)d_in[0];
    const float* Wq  = (const float*)d_in[1];
    const float* Wkv = (const float*)d_in[2];
    const float* Wk  = (const float*)d_in[3];
    const float* Wv  = (const float*)d_in[4];
    const float* Wo  = (const float*)d_in[5];
    const float* qg  = (const float*)d_in[6];
    const float* kg  = (const float*)d_in[7];

    char* base  = (char*)d_ws + 64;
    float* qraw = (float*)(base + 0);
    float* kpre = (float*)(base + 0);          // alias, live after qrms
    float* vraw = (float*)(base + 16777216);
    float* att  = (float*)(base + 0);          // alias, live after kv_split
    bf16*  qn   = (bf16*)(base + 33554432);
    bf16*  kn   = (bf16*)(base + 41943040);
    bf16*  vb   = (bf16*)(base + 50331648);
    float* kv   = (float*)(base + 58720256);

    const int BT = BB * TT;                    // 8192

    // 1. qraw = x @ Wq   (8192 x 1024, K=1024)
    naive_gemm<<<(int)(((long long)BT * DD + 255) / 256), 256, 0, stream>>>(
        x, Wq, qraw, BT, DD, DD);
    // 2. qn = rmsnorm_64(qraw)[:32] -> (b,h,t,32)
    qrms_kernel<<<(BT * HH * 64) / 256, 256, 0, stream>>>(qraw, qg, qn);
    // 3. kv = x @ Wkv    (8192 x 128, K=1024)
    naive_gemm<<<(int)(((long long)BT * LAT_ + 255) / 256), 256, 0, stream>>>(
        x, Wkv, kv, BT, LAT_, DD);
    // 4. kpre = kv @ Wk ; vraw = kv @ Wv   (8192 x 512, K=128) — overwrites qraw
    naive_gemm<<<(int)(((long long)BT * 512 + 255) / 256), 256, 0, stream>>>(
        kv, Wk, kpre, BT, 512, LAT_);
    naive_gemm<<<(int)(((long long)BT * 512 + 255) / 256), 256, 0, stream>>>(
        kv, Wv, vraw, BT, 512, LAT_);
    // 5. kn = rmsnorm_32(kpre), v relayout -> (b,h,t,32)
    kv_split_kernel<<<(BT * HH * 64) / 256, 256, 0, stream>>>(
        kpre, vraw, kg, kn, vb);
    // 6. causal attention -> att fp32 (bt, h*64+c), zero-padded
    attn_naive<<<dim3(TT, BB * HH), 64, 0, stream>>>(qn, kn, vb, att);
    // 7. out = att @ Wo  (8192 x 1024, K=1024), FP32 out
    naive_gemm<<<outgrid, 256, 0, stream>>>(att, Wo, out, BT, DD, DD);
}

// Round 15
// 2587.579 us; speedup vs baseline: 3.1687x; 3.1687x over previous
//
#include <hip/hip_runtime.h>
#include <hip/hip_bf16.h>
#include <math.h>

using bf16 = __hip_bfloat16;
typedef __attribute__((ext_vector_type(8))) short bf16x8;
typedef __attribute__((ext_vector_type(4))) float f32x4;

#define BB   4
#define TT   2048
#define DD   1024
#define HH   16
#define HD_  64
#define LAT_ 128
#define RP   32
#define EPS_ 1e-6f

static __device__ __forceinline__ void stf(float* p, float v) { *p = v; }
static __device__ __forceinline__ void stf(bf16* p, float v) { *p = __float2bfloat16(v); }

__global__ __launch_bounds__(256)
void sentinel_kernel(float* __restrict__ out, float val, long long n)
{
    long long i = (long long)blockIdx.x * 256 + threadIdx.x;
    if (i < n) out[i] = val;
}

// ---------------------------------------------------------------------------
// Converters (one-time, memory-bound, ~30 us total)
// ---------------------------------------------------------------------------
__global__ __launch_bounds__(256)
void conv_x_kernel(const float* __restrict__ x, bf16* __restrict__ xb, long long n)
{
    long long i = (long long)blockIdx.x * 256 + threadIdx.x;
    if (i < n) xb[i] = __float2bfloat16(x[i]);
}

// W (K x N fp32 row-major) -> WT (N x K bf16): WT[n*K+k] = W[k*N+n]
__global__ __launch_bounds__(256)
void conv_wT_kernel(const float* __restrict__ W, bf16* __restrict__ WT, int K, int N)
{
    long long idx = (long long)blockIdx.x * 256 + threadIdx.x;
    if (idx >= (long long)K * N) return;
    int k = (int)(idx / N), n = (int)(idx % N);
    WT[(size_t)n * K + k] = __float2bfloat16(W[idx]);
}

// [Wk | Wv] (each 128x512) -> WT (1024 x 128): rows 0..511 = Wk cols,
// rows 512..1023 = Wv cols.
__global__ __launch_bounds__(256)
void conv_wkwv_kernel(const float* __restrict__ Wk, const float* __restrict__ Wv,
                      bf16* __restrict__ WT)
{
    int idx = blockIdx.x * 256 + threadIdx.x;      // 128*1024
    if (idx >= 128 * 1024) return;
    int k = idx >> 10, n = idx & 1023;
    float v = (n < 512) ? Wk[k * 512 + n] : Wv[k * 512 + (n - 512)];
    WT[(size_t)n * 128 + k] = __float2bfloat16(v);
}

// Wo (1024x1024) -> woT (1024 x 512) with row remap: woT[n*512+m] =
// Wo[((m>>5)<<6 | (m&31))*1024 + n]  (skips zero-padded head dims)
__global__ __launch_bounds__(256)
void conv_woT_kernel(const float* __restrict__ Wo, bf16* __restrict__ WT)
{
    int idx = blockIdx.x * 256 + threadIdx.x;      // 512*1024
    if (idx >= 512 * 1024) return;
    int mm = idx >> 10, n = idx & 1023;
    int row = ((mm >> 5) << 6) | (mm & 31);
    WT[(size_t)n * 512 + mm] = __float2bfloat16(Wo[(size_t)row * 1024 + n]);
}

// ---------------------------------------------------------------------------
// MFMA GEMM: C[M,N] = A[M,K] @ B[K,N], A bf16 row-major (M x K), BT bf16
// row-major (N x K) — the B^T-input pattern. 128x128 tile, BK=32, 256 thr
// (4 waves), each wave a 64x64 quadrant via 4x4 mfma_f32_16x16x32_bf16.
// Fragment maps (HW-verified per guide): A[m=lane&15][k=quad*8+j],
// BT[n=lane&15][k=quad*8+j], C/D row=quad*4+reg, col=lane&15.
// M % 128 == 0, N % 128 == 0, K % 32 == 0.
// ---------------------------------------------------------------------------
template <typename OT>
__global__ __launch_bounds__(256)
void gemm_mfma(const short* __restrict__ A, const short* __restrict__ BT,
               OT* __restrict__ C, int M, int N, int K)
{
    __shared__ __align__(16) short As[128][32];
    __shared__ __align__(16) short Bs[128][32];
    const int tid  = threadIdx.x;
    const int wave = tid >> 6, lane = tid & 63;
    const int quad = lane >> 4, l16 = lane & 15;
    const int wr = (wave >> 1) * 64, wc = (wave & 1) * 64;
    const int row0 = blockIdx.y * 128, col0 = blockIdx.x * 128;
    const int srow = tid >> 1, skoff = (tid & 1) * 16;   // staging map

    f32x4 acc[4][4];
    #pragma unroll
    for (int mt = 0; mt < 4; ++mt)
        #pragma unroll
        for (int nt = 0; nt < 4; ++nt)
            acc[mt][nt] = (f32x4){0.f, 0.f, 0.f, 0.f};

    for (int k0 = 0; k0 < K; k0 += 32) {
        const short* ga = A  + (size_t)(row0 + srow) * K + k0 + skoff;
        const short* gb = BT + (size_t)(col0 + srow) * K + k0 + skoff;
        uint4 va0 = *(const uint4*)ga;
        uint4 va1 = *(const uint4*)(ga + 8);
        uint4 vb0 = *(const uint4*)gb;
        uint4 vb1 = *(const uint4*)(gb + 8);
        __syncthreads();
        *(uint4*)&As[srow][skoff]     = va0;
        *(uint4*)&As[srow][skoff + 8] = va1;
        *(uint4*)&Bs[srow][skoff]     = vb0;
        *(uint4*)&Bs[srow][skoff + 8] = vb1;
        __syncthreads();

        bf16x8 af[4], bfv[4];
        #pragma unroll
        for (int mt = 0; mt < 4; ++mt)
            af[mt] = *(const bf16x8*)&As[wr + mt * 16 + l16][quad * 8];
        #pragma unroll
        for (int nt = 0; nt < 4; ++nt)
            bfv[nt] = *(const bf16x8*)&Bs[wc + nt * 16 + l16][quad * 8];
        #pragma unroll
        for (int mt = 0; mt < 4; ++mt)
            #pragma unroll
            for (int nt = 0; nt < 4; ++nt)
                acc[mt][nt] = __builtin_amdgcn_mfma_f32_16x16x32_bf16(
                    af[mt], bfv[nt], acc[mt][nt], 0, 0, 0);
    }

    #pragma unroll
    for (int mt = 0; mt < 4; ++mt)
        #pragma unroll
        for (int nt = 0; nt < 4; ++nt) {
            const int col = col0 + wc + nt * 16 + l16;
            #pragma unroll
            for (int r = 0; r < 4; ++r) {
                const int row = row0 + wr + mt * 16 + quad * 4 + r;
                stf(C + (size_t)row * N + col, acc[mt][nt][r]);
            }
        }
}

// ---------------------------------------------------------------------------
// Q RMSNorm: one wave64 per (bt, h); rms over 64 head dims (bf16 in);
// write first 32 normalized dims to qn bf16 (b,h,t,32).
// ---------------------------------------------------------------------------
__global__ __launch_bounds__(256)
void qrms_kernel(const bf16* __restrict__ qraw, const float* __restrict__ qg,
                 bf16* __restrict__ qn)
{
    const int gid  = blockIdx.x * 256 + threadIdx.x;
    const int lane = gid & 63;
    const int grp  = gid >> 6;
    const int bt   = grp >> 4;
    const int h    = grp & 15;
    float v = __bfloat162float(qraw[(size_t)bt * DD + h * HD_ + lane]);
    float s = v * v;
    #pragma unroll
    for (int off = 32; off; off >>= 1) s += __shfl_xor(s, off, 64);
    const float inv = 1.0f / sqrtf(s * (1.0f / HD_) + EPS_);
    if (lane < RP) {
        const int b = bt >> 11, t = bt & 2047;
        qn[(((size_t)(b * HH + h)) * TT + t) * RP + lane] =
            __float2bfloat16(qg[lane] * v * inv);
    }
}

// ---------------------------------------------------------------------------
// K RMSNorm (lanes 0..31) + V relayout (lanes 32..63) from combined
// kvout fp32 (bt, 1024): cols 0..511 = kpre, 512..1023 = vraw.
// Out: kn/vb bf16 (b,h,t,32).
// ---------------------------------------------------------------------------
__global__ __launch_bounds__(256)
void kv_split_kernel(const float* __restrict__ kvout, const float* __restrict__ kg,
                     bf16* __restrict__ kn, bf16* __restrict__ vout)
{
    const int gid  = blockIdx.x * 256 + threadIdx.x;
    const int lane = gid & 63;
    const int grp  = gid >> 6;
    const int bt   = grp >> 4;
    const int h    = grp & 15;
    const int b = bt >> 11, t = bt & 2047;
    const size_t dst = (((size_t)(b * HH + h)) * TT + t) * RP;
    if (lane < 32) {
        float v = kvout[(size_t)bt * 1024 + h * 32 + lane];
        float s = v * v;
        #pragma unroll
        for (int off = 16; off; off >>= 1) s += __shfl_xor(s, off, 32);
        const float inv = 1.0f / sqrtf(s * (1.0f / RP) + EPS_);
        kn[dst + lane] = __float2bfloat16(kg[lane] * v * inv);
    } else {
        const int j = lane - 32;
        vout[dst + j] = __float2bfloat16(kvout[(size_t)bt * 1024 + 512 + h * 32 + j]);
    }
}

// ---------------------------------------------------------------------------
// Two-pass causal attention (validated R14): one wave64 per (b,h,t) row.
// NOW writes compact bf16 att (b, t, h*32+c) — no zero pad (out-proj uses
// the 512-row remapped woT).
// ---------------------------------------------------------------------------
__global__ __launch_bounds__(64)
void attn_naive(const bf16* __restrict__ qn, const bf16* __restrict__ kn,
                const bf16* __restrict__ vv, bf16* __restrict__ att)
{
    const int t    = blockIdx.x;
    const int bh   = blockIdx.y;
    const int lane = threadIdx.x;

    const bf16* qp = qn + ((size_t)bh * TT + t) * RP;
    float q[RP];
    #pragma unroll
    for (int j = 0; j < RP; ++j) q[j] = __bfloat162float(qp[j]) * 0.125f;

    float mloc = -1e30f;
    for (int s = lane; s <= t; s += 64) {
        const bf16* kp = kn + ((size_t)bh * TT + s) * RP;
        float d = 0.f;
        #pragma unroll
        for (int j = 0; j < RP; ++j) d = fmaf(q[j], __bfloat162float(kp[j]), d);
        mloc = fmaxf(mloc, d);
    }
    #pragma unroll
    for (int off = 32; off; off >>= 1) mloc = fmaxf(mloc, __shfl_xor(mloc, off, 64));

    float l = 0.f;
    float acc[RP];
    #pragma unroll
    for (int c = 0; c < RP; ++c) acc[c] = 0.f;
    for (int s = lane; s <= t; s += 64) {
        const bf16* kp = kn + ((size_t)bh * TT + s) * RP;
        float d = 0.f;
        #pragma unroll
        for (int j = 0; j < RP; ++j) d = fmaf(q[j], __bfloat162float(kp[j]), d);
        const float p = __expf(d - mloc);
        l += p;
        const bf16* vp = vv + ((size_t)bh * TT + s) * RP;
        #pragma unroll
        for (int c = 0; c < RP; ++c)
            acc[c] = fmaf(p, __bfloat162float(vp[c]), acc[c]);
    }
    #pragma unroll
    for (int off = 32; off; off >>= 1) l += __shfl_xor(l, off, 64);
    #pragma unroll
    for (int c = 0; c < RP; ++c) {
        float a = acc[c];
        #pragma unroll
        for (int off = 32; off; off >>= 1) a += __shfl_xor(a, off, 64);
        acc[c] = a;
    }

    if (lane == 0) {
        const int b = bh >> 4, h = bh & 15;
        const float inv = 1.0f / l;
        bf16* op = att + ((size_t)(b * TT + t)) * 512 + h * 32;
        #pragma unroll
        for (int c = 0; c < RP; ++c) op[c] = __float2bfloat16(acc[c] * inv);
    }
}

// ---------------------------------------------------------------------------
// Workspace (BYTE offsets from base = d_ws + 64; fits verified 60 MB):
//   xb    bf16 [0, 16777216)            (dead after GEMM2)
//   wqT   bf16 [16777216, 18874368)     (dead after GEMM1)
//   wkvT  bf16 [18874368, 19136512)     (dead after GEMM2)
//   qrawb bf16 [19136512, 35913728)     (dead after qrms)
//   kvb   bf16 [33554432, 35651584)     (alias in dead qrawb tail; GEMM2 out)
//   kvout fp32 [0, 33554432)            (alias over dead xb/wqT/wkvT/qrawb-head)
//   att_b bf16 [0, 8388608)             (alias over dead kvout)
//   qn    bf16 [35913728, 44302336)
//   kn    bf16 [44302336, 52690944)
//   vb    bf16 [52690944, 61079552)
//   wkwvT bf16 [61079552, 61341696)
//   woT   bf16 [61341696, 62390272)
// ---------------------------------------------------------------------------
extern "C" void kernel_launch(void* const* d_in, const int* in_sizes, int n_in,
                              void* d_out, int out_size, void* d_ws, size_t ws_size,
                              hipStream_t stream)
{
    float* out = (float*)d_out;                     // FP32 output (R14 fix)
    const long long NOUT = (long long)BB * TT * DD;
    const int outgrid = (int)((NOUT + 255) / 256);

    static const long long expect[8] =
        {8388608, 1048576, 131072, 65536, 65536, 1048576, 64, 32};
    if (n_in != 8) {
        sentinel_kernel<<<outgrid, 256, 0, stream>>>(out, 20000.0f + 100.0f * n_in, NOUT);
        return;
    }
    for (int i = 0; i < 8; ++i) {
        if ((long long)in_sizes[i] != expect[i]) {
            sentinel_kernel<<<outgrid, 256, 0, stream>>>(out, 10000.0f + 1000.0f * i, NOUT);
            return;
        }
    }
    if (ws_size < 62914624ULL) {
        sentinel_kernel<<<outgrid, 256, 0, stream>>>(
            out, 30000.0f + (float)(ws_size >> 20), NOUT);
        return;
    }
    if (out_size != 8388608) {
        sentinel_kernel<<<outgrid, 256, 0, stream>>>(
            out, 512.0f * (1.0f + (float)(out_size >> 20)), NOUT);
        return;
    }

    const float* x   = (const float*)d_in[0];
    const float* Wq  = (const float*)d_in[1];
    const float* Wkv = (const float*)d_in[2];
    const float* Wk  = (const float*)d_in[3];
    const float* Wv  = (const float*)d_in[4];
    const float* Wo  = (const float*)d_in[5];
    const float* qg  = (const float*)d_in[6];
    const float* kg  = (const float*)d_in[7];

    char* base = (char*)d_ws + 64;
    bf16*  xb    = (bf16*)(base + 0);
    bf16*  wqT   = (bf16*)(base + 16777216);
    bf16*  wkvT  = (bf16*)(base + 18874368);
    bf16*  qrawb = (bf16*)(base + 19136512);
    bf16*  kvb   = (bf16*)(base + 33554432);
    float* kvout = (float*)(base + 0);
    bf16*  att_b = (bf16*)(base + 0);
    bf16*  qn    = (bf16*)(base + 35913728);
    bf16*  kn    = (bf16*)(base + 44302336);
    bf16*  vb    = (bf16*)(base + 52690944);
    bf16*  wkwvT = (bf16*)(base + 61079552);
    bf16*  woT   = (bf16*)(base + 61341696);

    const int BT = BB * TT;                    // 8192

    // 0. converts
    conv_x_kernel<<<outgrid, 256, 0, stream>>>(x, xb, NOUT);
    conv_wT_kernel<<<4096, 256, 0, stream>>>(Wq, wqT, 1024, 1024);
    conv_wT_kernel<<<512, 256, 0, stream>>>(Wkv, wkvT, 1024, 128);
    conv_wkwv_kernel<<<512, 256, 0, stream>>>(Wk, Wv, wkwvT);
    conv_woT_kernel<<<2048, 256, 0, stream>>>(Wo, woT);

    // 1. qrawb = xb @ Wq (MFMA), 8192x1024, K=1024
    gemm_mfma<bf16><<<dim3(8, 64), 256, 0, stream>>>(
        (const short*)xb, (const short*)wqT, qrawb, BT, DD, DD);
    // 2. qn = rmsnorm_64(qrawb)[:32]
    qrms_kernel<<<(BT * HH * 64) / 256, 256, 0, stream>>>(qrawb, qg, qn);
    // 3. kvb = xb @ Wkv (MFMA), 8192x128, K=1024
    gemm_mfma<bf16><<<dim3(1, 64), 256, 0, stream>>>(
        (const short*)xb, (const short*)wkvT, kvb, BT, LAT_, DD);
    // 4. kvout = kvb @ [Wk|Wv] (MFMA), 8192x1024, K=128
    gemm_mfma<float><<<dim3(8, 64), 256, 0, stream>>>(
        (const short*)kvb, (const short*)wkwvT, kvout, BT, 2 * 512, LAT_);
    // 5. kn/vb from kvout
    kv_split_kernel<<<(BT * HH * 64) / 256, 256, 0, stream>>>(kvout, kg, kn, vb);
    // 6. attention -> att_b bf16 (bt, 512)
    attn_naive<<<dim3(TT, BB * HH), 64, 0, stream>>>(qn, kn, vb, att_b);
    // 7. out = att_b @ Wo_remap (MFMA), 8192x1024, K=512
    gemm_mfma<float><<<dim3(8, 64), 256, 0, stream>>>(
        (const short*)att_b, (const short*)woT, out, BT, DD, 512);
}